// Round 4
// baseline (223.884 us; speedup 1.0000x reference)
//
#include <hip/hip_runtime.h>
#include <hip/hip_bf16.h>

// ProbSFNO — algebraically collapsed: only m=0 spherical modes reach the output.
// filt_i is mathematically dead; per-layer state is a (B,EMBED) vector D.
// R1: split-K chain. R2: fused kg+ka. R3 (this): 3 launches total —
// k2 folded into k3 (per-block q recompute), whole layer chain + kfin + kout
// fused into one 128-block kernel with hand-rolled grid barriers
// (128 blocks <= 256 CUs => co-residency guaranteed; counters re-zeroed by k01
// every call => graph-replay deterministic).

namespace {

constexpr float kTwoPi = 6.283185307179586f;
constexpr int NKC = 16;   // split-K chunks in the layer chain
constexpr int NBLK = 128; // kchain grid (co-resident: 128 <= 256 CUs)

// ws layout (float offsets)
constexpr int WS_PW0  = 16;                  // [48][121] Pmat[l,0,j]*wq[j]
constexpr int WS_PBAR = 5824;                // [48] mean_j Pmat[l,0,j]
constexpr int WS_TW   = 5872;                // [48] 2pi*Pbar*SW
constexpr int WS_XBAR = 5920;                // [4][5][121] mean_lon x
constexpr int WS_BAR  = 8352;                // [64] int barrier counters
constexpr int WS_T    = 16384;               // [4][256][256]
constexpr int WS_PART = 278528;              // [4][64][4][256] term1 partials
constexpr int WS_DP   = 540672;              // [4lay][4b][16][256] delta partials
constexpr int WS_A1P  = 606208;              // [4lay][4b][16][512] mlp1 partials
constexpr int WS_W4   = 737280;              // [20] w_out·w_in
constexpr int WS_BIAS = 737300;              // [16] per-(b,o4) output bias

struct Args {
  const void *x, *eps, *Pmat, *wq, *w_in, *b_in, *filt_r;
  const void *w1, *b1, *w2, *b2, *w_out, *b_out;
  float* ws;
  void* out;
};

__device__ __forceinline__ float bf2f(unsigned short u) {
  union { unsigned int i; float f; } v; v.i = (unsigned int)u << 16; return v.f;
}
__device__ __forceinline__ unsigned short f2bf(float f) {
  union { float f; unsigned int i; } v; v.f = f;
  return (unsigned short)((v.i + 0x7FFFu + ((v.i >> 16) & 1u)) >> 16);
}
// Local dtype detect: wq[0] = 3.37e-4 if f32; a bf16-pair misread gives ~1e-3.
__device__ __forceinline__ int detect_bf(const void* wq) {
  float v = ((const float*)wq)[0];
  return !(v > 2.5e-4f && v < 4.5e-4f);
}
__device__ __forceinline__ float ldf(const void* p, long i, int bf) {
  return bf ? bf2f(((const unsigned short*)p)[i]) : ((const float*)p)[i];
}
__device__ __forceinline__ float4 ld4(const void* p, long e, int bf) {
  if (bf) {
    ushort4 u = *(const ushort4*)((const unsigned short*)p + e);
    return make_float4(bf2f(u.x), bf2f(u.y), bf2f(u.z), bf2f(u.w));
  }
  return *(const float4*)((const float*)p + e);
}
__device__ __forceinline__ void st4(void* p, long e, float a, float b, float c,
                                    float d, int bf) {
  if (bf) {
    ushort4 u; u.x = f2bf(a); u.y = f2bf(b); u.z = f2bf(c); u.w = f2bf(d);
    *(ushort4*)((unsigned short*)p + e) = u;
  } else {
    *(float4*)((float*)p + e) = make_float4(a, b, c, d);
  }
}

// Grid barrier: all NBLK blocks arrive (one device-scope atomic each), thread 0
// spins. Counters zeroed by k01 each kernel_launch => deterministic per replay.
__device__ __forceinline__ void gbar(int* bars, int id, int n) {
  __threadfence();
  __syncthreads();
  if (threadIdx.x == 0) {
    atomicAdd(&bars[id], 1);
    while (atomicAdd(&bars[id], 0) < n) __builtin_amdgcn_s_sleep(2);
  }
  __syncthreads();
}

// K01: blocks 0..604 = lon-means of x (4 waves/block, 2420 rows);
// block 605 = Legendre precomputes + barrier-counter zeroing.
__global__ void k01_prep_xbar(Args A) {
  int bf = detect_bf(A.wq);
  float* ws = A.ws;
  int t = threadIdx.x;
  if (blockIdx.x == 605) {
    if (t < 64) ((int*)(ws + WS_BAR))[t] = 0;
    for (int idx = t; idx < 48 * 121; idx += 256) {
      int l = idx / 121, j = idx - l * 121;
      float p = ldf(A.Pmat, (long)l * 48 * 121 + j, bf);  // Pmat[l][0][j]
      float w = ldf(A.wq, j, bf);
      ws[WS_PW0 + idx] = p * w;
    }
    if (t < 48) {
      float pb = 0.f, sw = 0.f;
      for (int j = 0; j < 121; ++j) {
        float p = ldf(A.Pmat, (long)t * 48 * 121 + j, bf);
        float w = ldf(A.wq, j, bf);
        pb += p; sw += p * w;
      }
      pb *= (1.0f / 121.0f);
      ws[WS_PBAR + t] = pb;
      ws[WS_TW + t] = kTwoPi * pb * sw;
    }
    return;
  }
  int wave = blockIdx.x * 4 + (t >> 6);
  int lane = t & 63;
  long base = (long)wave * 240;
  float s = 0.f;
  for (int e = lane; e < 240; e += 64) s += ldf(A.x, base + e, bf);
  for (int d = 32; d; d >>= 1) s += __shfl_xor(s, d, 64);
  if (lane == 0) ws[WS_XBAR + wave] = s * (1.0f / 240.0f);
}

// K3q: per-block q recompute (replaces k2) + filt_r stream -> T, PART.
// Also warms w1/w2 (4 MB) into L3 for the chain kernel.
__global__ void __launch_bounds__(256) k3q(Args A) {
  __shared__ float pw0[48 * 121];   // 23.2 KB
  __shared__ float g0[16][121];     // 7.7 KB, pair = b*4+ci
  __shared__ float qs[4][4][48];    // qs[b][ci][l] = q * Pbar[l]
  __shared__ float twl[48];
  int bf = detect_bf(A.wq);
  int t = threadIdx.x;
  int bx = blockIdx.x;
  int lay = bx >> 8;
  int rem = bx & 255;
  int cb = rem >> 2, ob = rem & 3;
  int c0 = cb * 4, o0 = ob * 64;
  int ol = t >> 2, lq = t & 3;  // thread owns (o0+ol, l in [lq*12, lq*12+12))
  float* ws = A.ws;
  if (t < 48) twl[t] = ws[WS_TW + t];
  for (int ii = t; ii < 48 * 121; ii += 256) pw0[ii] = ws[WS_PW0 + ii];
  for (int ii = t; ii < 16 * 121; ii += 256) {
    int pair = ii / 121, j = ii - pair * 121;
    int bb = pair >> 2, ci = pair & 3, c = c0 + ci;
    float h = ldf(A.b_in, c, bf);
#pragma unroll
    for (int ic = 0; ic < 5; ++ic)
      h += ldf(A.w_in, c * 5 + ic, bf) * ws[WS_XBAR + (bb * 5 + ic) * 121 + j];
    g0[pair][j] = kTwoPi * h;
  }
  __syncthreads();
  for (int dd = t; dd < 768; dd += 256) {
    int pair = dd / 48, l = dd - pair * 48;
    float q = 0.f;
    const float* pw = &pw0[l * 121];
    const float* g = &g0[pair][0];
    for (int j = 0; j < 121; ++j) q += g[j] * pw[j];
    qs[pair >> 2][pair & 3][l] = q * ws[WS_PBAR + l];
  }
  __syncthreads();

  float acc0 = 0.f, acc1 = 0.f, acc2 = 0.f, acc3 = 0.f;
#pragma unroll
  for (int ci = 0; ci < 4; ++ci) {
    int c = c0 + ci;
    long base = ((long)((lay * 256 + c) * 256 + (o0 + ol))) * 48 + lq * 12;
    float f[12];
    if (bf) {
      const uint2* up = (const uint2*)((const unsigned short*)A.filt_r + base);
      uint2 u0 = up[0], u1 = up[1], u2 = up[2];
      f[0] = bf2f((unsigned short)(u0.x & 0xFFFFu)); f[1] = bf2f((unsigned short)(u0.x >> 16));
      f[2] = bf2f((unsigned short)(u0.y & 0xFFFFu)); f[3] = bf2f((unsigned short)(u0.y >> 16));
      f[4] = bf2f((unsigned short)(u1.x & 0xFFFFu)); f[5] = bf2f((unsigned short)(u1.x >> 16));
      f[6] = bf2f((unsigned short)(u1.y & 0xFFFFu)); f[7] = bf2f((unsigned short)(u1.y >> 16));
      f[8] = bf2f((unsigned short)(u2.x & 0xFFFFu)); f[9] = bf2f((unsigned short)(u2.x >> 16));
      f[10] = bf2f((unsigned short)(u2.y & 0xFFFFu)); f[11] = bf2f((unsigned short)(u2.y >> 16));
    } else {
      const float4* fp = (const float4*)((const float*)A.filt_r + base);
      float4 v0 = fp[0], v1 = fp[1], v2 = fp[2];
      f[0] = v0.x; f[1] = v0.y; f[2] = v0.z; f[3] = v0.w;
      f[4] = v1.x; f[5] = v1.y; f[6] = v1.z; f[7] = v1.w;
      f[8] = v2.x; f[9] = v2.y; f[10] = v2.z; f[11] = v2.w;
    }
    float tacc = 0.f;
    int lb = lq * 12;
#pragma unroll
    for (int r = 0; r < 12; ++r) {
      float fv = f[r];
      int l = lb + r;
      tacc += fv * twl[l];
      acc0 += fv * qs[0][ci][l];
      acc1 += fv * qs[1][ci][l];
      acc2 += fv * qs[2][ci][l];
      acc3 += fv * qs[3][ci][l];
    }
    tacc += __shfl_xor(tacc, 1, 64);
    tacc += __shfl_xor(tacc, 2, 64);
    if (lq == 0) ws[WS_T + ((lay * 256 + c) * 256) + o0 + ol] = tacc;
  }
  acc0 += __shfl_xor(acc0, 1, 64); acc0 += __shfl_xor(acc0, 2, 64);
  acc1 += __shfl_xor(acc1, 1, 64); acc1 += __shfl_xor(acc1, 2, 64);
  acc2 += __shfl_xor(acc2, 1, 64); acc2 += __shfl_xor(acc2, 2, 64);
  acc3 += __shfl_xor(acc3, 1, 64); acc3 += __shfl_xor(acc3, 2, 64);
  if (lq == 0) {
    int po = o0 + ol;
    long pb = (long)(lay * 64 + cb) * 4 * 256;
    ws[WS_PART + pb + 0 * 256 + po] = acc0;
    ws[WS_PART + pb + 1 * 256 + po] = acc1;
    ws[WS_PART + pb + 2 * 256 + po] = acc2;
    ws[WS_PART + pb + 3 * 256 + po] = acc3;
  }
  // L3 warm: touch w1/w2 so the chain kernel hits Infinity Cache, not cold HBM.
  if (bx < 32) {
    long nbytes = 524288L * (bf ? 2 : 4);
    long per = nbytes / 32;
    long off = (long)bx * per;
    const char* p1 = (const char*)A.w1;
    const char* p2 = (const char*)A.w2;
    float acc = 0.f;
    for (long i = (long)t * 16; i < per; i += 256 * 16) {
      float4 v1 = *(const float4*)(p1 + off + i);
      float4 v2 = *(const float4*)(p2 + off + i);
      acc += v1.x + v2.x;
    }
    asm volatile("" :: "v"(acc));
  }
}

// kchain: entire 4-layer MLP chain + kfin + kout in one kernel.
// Blocks 0..63 do the chain phases; all 128 blocks hit every barrier; all 128
// do the final elementwise output. Volatile loads for cross-barrier ws reads.
__global__ void __launch_bounds__(256) kchain(Args A) {
  __shared__ float sDl[256];
  __shared__ float sGsh[16];
  __shared__ float sAl[32];
  __shared__ float sDsh[256];
  __shared__ float sW4[20];
  __shared__ float sBias[16];
  int bf = detect_bf(A.wq);
  int t = threadIdx.x;
  int blk = blockIdx.x;  // 128
  float* ws = A.ws;
  int* bars = (int*)(ws + WS_BAR);
  int b = (blk >> 4) & 3, kc = blk & 15;
  int grp = t >> 4, i = t & 15;

  for (int lay = 0; lay < 4; ++lay) {
    if (blk < 64) {  // phase A: finalize D, g = PART + D@T, mlp1 partials
      int o0 = kc * 16;
      float d = 0.f;
      for (int l = 0; l < 3; ++l)
        if (l < lay)
          for (int k2 = 0; k2 < NKC; ++k2)
            d += *(volatile float*)(ws + WS_DP + (((l * 4 + b) * NKC + k2) * 256) + t);
      sDl[t] = d;
      float s = 0.f;
#pragma unroll
      for (int u = 0; u < 4; ++u)
        s += ws[WS_PART + (((lay * 64 + (i * 4 + u)) * 4 + b) * 256) + o0 + grp];
      __syncthreads();
      if (lay) {
#pragma unroll
        for (int u = 0; u < 16; ++u)
          s += sDl[u * 16 + i] * ws[WS_T + ((lay * 256 + u * 16 + i) * 256) + o0 + grp];
      }
      s += __shfl_xor(s, 1, 64);
      s += __shfl_xor(s, 2, 64);
      s += __shfl_xor(s, 4, 64);
      s += __shfl_xor(s, 8, 64);
      if (i == 0) sGsh[grp] = s;
      __syncthreads();
      float s0 = 0.f, s1 = 0.f;
#pragma unroll
      for (int u = 0; u < 16; ++u) {
        float g = sGsh[u];
        long base = ((long)(lay * 256 + o0 + u)) * 512;
        s0 += g * ldf(A.w1, base + t, bf);
        s1 += g * ldf(A.w1, base + t + 256, bf);
      }
      ws[WS_A1P + (((lay * 4 + b) * NKC + kc) * 512) + t] = s0;
      ws[WS_A1P + (((lay * 4 + b) * NKC + kc) * 512) + t + 256] = s1;
    }
    gbar(bars, lay * 2, NBLK);
    if (blk < 64) {  // phase B: finalize act (gelu), delta partials
      int h0 = kc * 32;
      if (t < 32) {
        float v = ldf(A.b1, lay * 512 + h0 + t, bf);
        for (int k2 = 0; k2 < NKC; ++k2)
          v += *(volatile float*)(ws + WS_A1P + (((lay * 4 + b) * NKC + k2) * 512) + h0 + t);
        sAl[t] = 0.5f * v * (1.0f + erff(v * 0.7071067811865475f));
      }
      __syncthreads();
      float s = (kc == 0) ? ldf(A.b2, lay * 256 + t, bf) : 0.f;
#pragma unroll
      for (int u = 0; u < 32; ++u)
        s += sAl[u] * ldf(A.w2, ((long)(lay * 512 + h0 + u)) * 256 + t, bf);
      ws[WS_DP + (((lay * 4 + b) * NKC + kc) * 256) + t] = s;
    }
    gbar(bars, lay * 2 + 1, NBLK);
  }

  // kfin: per-(b,o4) output bias; block 0 also computes w_out·w_in (20 vals).
  if (blk < 4) {
    float d = 0.f;
    for (int l = 0; l < 4; ++l)
      for (int k = 0; k < NKC; ++k)
        d += *(volatile float*)(ws + WS_DP + (((l * 4 + blk) * NKC + k) * 256) + t);
    sDsh[t] = d;
    __syncthreads();
    int o4 = t >> 6, sub = t & 63;
    float s = 0.f;
    for (int c = sub; c < 256; c += 64)
      s += ldf(A.w_out, o4 * 256 + c, bf) * (ldf(A.b_in, c, bf) + sDsh[c]);
    for (int dd = 32; dd; dd >>= 1) s += __shfl_xor(s, dd, 64);
    if (sub == 0) ws[WS_BIAS + blk * 4 + o4] = ldf(A.b_out, o4, bf) + s;
    if (blk == 0 && t < 160) {
      int e = t >> 3, sub8 = t & 7;  // e < 20
      int o4b = e / 5, ic = e - o4b * 5;
      float w = 0.f;
      for (int c = sub8; c < 256; c += 8)
        w += ldf(A.w_out, o4b * 256 + c, bf) * ldf(A.w_in, c * 5 + ic, bf);
      w += __shfl_xor(w, 1, 64);
      w += __shfl_xor(w, 2, 64);
      w += __shfl_xor(w, 4, 64);
      if (sub8 == 0) ws[WS_W4 + e] = w;
    }
  }
  gbar(bars, 8, NBLK);

  // kout: out = W4 @ x + bias; sample = mu + eps*exp(log_sigma).
  if (t < 20) sW4[t] = *(volatile float*)(ws + WS_W4 + t);
  if (t >= 32 && t < 48) sBias[t - 32] = *(volatile float*)(ws + WS_BIAS + t - 32);
  __syncthreads();
  int idx = blk * 256 + t;
  if (idx >= 4 * 121 * 60) return;
  int n4 = idx % 60;
  int j = (idx / 60) % 121;
  int bb = idx / (60 * 121);
  int n = n4 * 4;
  float4 xv[5];
#pragma unroll
  for (int ic = 0; ic < 5; ++ic)
    xv[ic] = ld4(A.x, ((long)((bb * 5 + ic) * 121 + j)) * 240 + n, bf);
  float v[4][4];
#pragma unroll
  for (int o4 = 0; o4 < 4; ++o4) {
    float bias = sBias[bb * 4 + o4];
    float s0 = bias, s1 = bias, s2 = bias, s3 = bias;
#pragma unroll
    for (int ic = 0; ic < 5; ++ic) {
      float w = sW4[o4 * 5 + ic];
      s0 += w * xv[ic].x; s1 += w * xv[ic].y;
      s2 += w * xv[ic].z; s3 += w * xv[ic].w;
    }
    v[o4][0] = s0; v[o4][1] = s1; v[o4][2] = s2; v[o4][3] = s3;
  }
  const long NPO = (long)4 * 2 * 121 * 240;  // 232320
#pragma unroll
  for (int oc = 0; oc < 2; ++oc) {
    long eoff = ((long)((bb * 2 + oc) * 121 + j)) * 240 + n;
    float4 ev = ld4(A.eps, eoff, bf);
    float e0 = expf(v[oc + 2][0]), e1 = expf(v[oc + 2][1]);
    float e2 = expf(v[oc + 2][2]), e3 = expf(v[oc + 2][3]);
    st4(A.out, eoff, v[oc][0] + ev.x * e0, v[oc][1] + ev.y * e1,
        v[oc][2] + ev.z * e2, v[oc][3] + ev.w * e3, bf);                // sample
    st4(A.out, NPO + eoff, v[oc][0], v[oc][1], v[oc][2], v[oc][3], bf); // mu
    st4(A.out, 2 * NPO + eoff, v[oc + 2][0], v[oc + 2][1], v[oc + 2][2],
        v[oc + 2][3], bf);                                              // log_sigma
  }
}

}  // namespace

extern "C" void kernel_launch(void* const* d_in, const int* in_sizes, int n_in,
                              void* d_out, int out_size, void* d_ws,
                              size_t ws_size, hipStream_t stream) {
  Args A;
  A.x = d_in[0]; A.eps = d_in[1]; A.Pmat = d_in[2]; A.wq = d_in[3];
  A.w_in = d_in[4]; A.b_in = d_in[5]; A.filt_r = d_in[6];
  // d_in[7] = filt_i: mathematically dead (m=0 coeffs are real).
  A.w1 = d_in[8]; A.b1 = d_in[9]; A.w2 = d_in[10]; A.b2 = d_in[11];
  A.w_out = d_in[12]; A.b_out = d_in[13];
  A.ws = (float*)d_ws;
  A.out = d_out;

  hipLaunchKernelGGL(k01_prep_xbar, dim3(606), dim3(256), 0, stream, A);
  hipLaunchKernelGGL(k3q, dim3(1024), dim3(256), 0, stream, A);
  hipLaunchKernelGGL(kchain, dim3(NBLK), dim3(256), 0, stream, A);
}

// Round 5
// 143.169 us; speedup vs baseline: 1.5638x; 1.5638x over previous
//
#include <hip/hip_runtime.h>
#include <hip/hip_bf16.h>

// ProbSFNO — algebraically collapsed: only m=0 spherical modes reach the output.
// filt_i is mathematically dead; per-layer state is a (B,EMBED) vector D.
// R3: 3 launches, grid-barrier fused chain. R4 post-mortem: RMW-spin barrier
// serialized (~20us/barrier). R5 (this): load-spin barrier, 1 barrier/layer
// (full-g per block kills the A1P exchange), idle blocks prefetch the output
// stage during the chain.

namespace {

constexpr float kTwoPi = 6.283185307179586f;
constexpr int NKC = 16;   // h-chunks (32 wide) / delta split in the chain
constexpr int NBLK = 128; // kchain grid (co-resident: 128 <= 256 CUs)
constexpr int NOUT_ITEMS = 4 * 121 * 60;  // 29040 float4-wide output items

// ws layout (float offsets)
constexpr int WS_PW0  = 16;                  // [48][121] Pmat[l,0,j]*wq[j]
constexpr int WS_PBAR = 5824;                // [48] mean_j Pmat[l,0,j]
constexpr int WS_TW   = 5872;                // [48] 2pi*Pbar*SW
constexpr int WS_XBAR = 5920;                // [4][5][121] mean_lon x
constexpr int WS_BAR  = 8352;                // [64] int barrier counters
constexpr int WS_T    = 16384;               // [4][256][256]
constexpr int WS_PART = 278528;              // [4][64][4][256] term1 partials
constexpr int WS_DP   = 540672;              // [4lay][4b][16][256] delta partials
constexpr int WS_W4   = 737280;              // [20] w_out·w_in
constexpr int WS_BIAS = 737300;              // [16] per-(b,o4) output bias

struct Args {
  const void *x, *eps, *Pmat, *wq, *w_in, *b_in, *filt_r;
  const void *w1, *b1, *w2, *b2, *w_out, *b_out;
  float* ws;
  void* out;
};

__device__ __forceinline__ float bf2f(unsigned short u) {
  union { unsigned int i; float f; } v; v.i = (unsigned int)u << 16; return v.f;
}
__device__ __forceinline__ unsigned short f2bf(float f) {
  union { float f; unsigned int i; } v; v.f = f;
  return (unsigned short)((v.i + 0x7FFFu + ((v.i >> 16) & 1u)) >> 16);
}
// Local dtype detect: wq[0] = 3.37e-4 if f32; a bf16-pair misread gives ~1e-3.
__device__ __forceinline__ int detect_bf(const void* wq) {
  float v = ((const float*)wq)[0];
  return !(v > 2.5e-4f && v < 4.5e-4f);
}
__device__ __forceinline__ float ldf(const void* p, long i, int bf) {
  return bf ? bf2f(((const unsigned short*)p)[i]) : ((const float*)p)[i];
}
__device__ __forceinline__ float4 ld4(const void* p, long e, int bf) {
  if (bf) {
    ushort4 u = *(const ushort4*)((const unsigned short*)p + e);
    return make_float4(bf2f(u.x), bf2f(u.y), bf2f(u.z), bf2f(u.w));
  }
  return *(const float4*)((const float*)p + e);
}
__device__ __forceinline__ void st4(void* p, long e, float a, float b, float c,
                                    float d, int bf) {
  if (bf) {
    ushort4 u; u.x = f2bf(a); u.y = f2bf(b); u.z = f2bf(c); u.w = f2bf(d);
    *(ushort4*)((unsigned short*)p + e) = u;
  } else {
    *(float4*)((float*)p + e) = make_float4(a, b, c, d);
  }
}

// Grid barrier, split arrive/wait. Arrival: one RELEASE atomicAdd per block
// (flushes this XCD's L2). Wait: RELAXED agent-scope atomic LOADS (sc1, no RMW
// serialization). Counters zeroed by k01 each launch => replay-deterministic.
__device__ __forceinline__ void gbar_arrive(int* bars, int id) {
  __syncthreads();  // drains vmcnt: all block stores at least in L2
  if (threadIdx.x == 0)
    __hip_atomic_fetch_add(&bars[id], 1, __ATOMIC_RELEASE,
                           __HIP_MEMORY_SCOPE_AGENT);
}
__device__ __forceinline__ void gbar_wait(int* bars, int id, int n) {
  if (threadIdx.x == 0) {
    while (__hip_atomic_load(&bars[id], __ATOMIC_RELAXED,
                             __HIP_MEMORY_SCOPE_AGENT) < n)
      __builtin_amdgcn_s_sleep(2);
  }
  __syncthreads();
}

// K01: blocks 0..604 = lon-means of x (4 waves/block, 2420 rows);
// block 605 = Legendre precomputes + barrier-counter zeroing.
__global__ void k01_prep_xbar(Args A) {
  int bf = detect_bf(A.wq);
  float* ws = A.ws;
  int t = threadIdx.x;
  if (blockIdx.x == 605) {
    if (t < 64) ((int*)(ws + WS_BAR))[t] = 0;
    for (int idx = t; idx < 48 * 121; idx += 256) {
      int l = idx / 121, j = idx - l * 121;
      float p = ldf(A.Pmat, (long)l * 48 * 121 + j, bf);  // Pmat[l][0][j]
      float w = ldf(A.wq, j, bf);
      ws[WS_PW0 + idx] = p * w;
    }
    if (t < 48) {
      float pb = 0.f, sw = 0.f;
      for (int j = 0; j < 121; ++j) {
        float p = ldf(A.Pmat, (long)t * 48 * 121 + j, bf);
        float w = ldf(A.wq, j, bf);
        pb += p; sw += p * w;
      }
      pb *= (1.0f / 121.0f);
      ws[WS_PBAR + t] = pb;
      ws[WS_TW + t] = kTwoPi * pb * sw;
    }
    return;
  }
  int wave = blockIdx.x * 4 + (t >> 6);
  int lane = t & 63;
  long base = (long)wave * 240;
  float s = 0.f;
  for (int e = lane; e < 240; e += 64) s += ldf(A.x, base + e, bf);
  for (int d = 32; d; d >>= 1) s += __shfl_xor(s, d, 64);
  if (lane == 0) ws[WS_XBAR + wave] = s * (1.0f / 240.0f);
}

// K3q: per-block q recompute + filt_r stream -> T, PART. Warms w1/w2 into L3.
__global__ void __launch_bounds__(256) k3q(Args A) {
  __shared__ float pw0[48 * 121];
  __shared__ float g0[16][121];
  __shared__ float qs[4][4][48];
  __shared__ float twl[48];
  int bf = detect_bf(A.wq);
  int t = threadIdx.x;
  int bx = blockIdx.x;
  int lay = bx >> 8;
  int rem = bx & 255;
  int cb = rem >> 2, ob = rem & 3;
  int c0 = cb * 4, o0 = ob * 64;
  int ol = t >> 2, lq = t & 3;  // thread owns (o0+ol, l in [lq*12, lq*12+12))
  float* ws = A.ws;
  if (t < 48) twl[t] = ws[WS_TW + t];
  for (int ii = t; ii < 48 * 121; ii += 256) pw0[ii] = ws[WS_PW0 + ii];
  for (int ii = t; ii < 16 * 121; ii += 256) {
    int pair = ii / 121, j = ii - pair * 121;
    int bb = pair >> 2, ci = pair & 3, c = c0 + ci;
    float h = ldf(A.b_in, c, bf);
#pragma unroll
    for (int ic = 0; ic < 5; ++ic)
      h += ldf(A.w_in, c * 5 + ic, bf) * ws[WS_XBAR + (bb * 5 + ic) * 121 + j];
    g0[pair][j] = kTwoPi * h;
  }
  __syncthreads();
  for (int dd = t; dd < 768; dd += 256) {
    int pair = dd / 48, l = dd - pair * 48;
    float q = 0.f;
    const float* pw = &pw0[l * 121];
    const float* g = &g0[pair][0];
    for (int j = 0; j < 121; ++j) q += g[j] * pw[j];
    qs[pair >> 2][pair & 3][l] = q * ws[WS_PBAR + l];
  }
  __syncthreads();

  float acc0 = 0.f, acc1 = 0.f, acc2 = 0.f, acc3 = 0.f;
#pragma unroll
  for (int ci = 0; ci < 4; ++ci) {
    int c = c0 + ci;
    long base = ((long)((lay * 256 + c) * 256 + (o0 + ol))) * 48 + lq * 12;
    float f[12];
    if (bf) {
      const uint2* up = (const uint2*)((const unsigned short*)A.filt_r + base);
      uint2 u0 = up[0], u1 = up[1], u2 = up[2];
      f[0] = bf2f((unsigned short)(u0.x & 0xFFFFu)); f[1] = bf2f((unsigned short)(u0.x >> 16));
      f[2] = bf2f((unsigned short)(u0.y & 0xFFFFu)); f[3] = bf2f((unsigned short)(u0.y >> 16));
      f[4] = bf2f((unsigned short)(u1.x & 0xFFFFu)); f[5] = bf2f((unsigned short)(u1.x >> 16));
      f[6] = bf2f((unsigned short)(u1.y & 0xFFFFu)); f[7] = bf2f((unsigned short)(u1.y >> 16));
      f[8] = bf2f((unsigned short)(u2.x & 0xFFFFu)); f[9] = bf2f((unsigned short)(u2.x >> 16));
      f[10] = bf2f((unsigned short)(u2.y & 0xFFFFu)); f[11] = bf2f((unsigned short)(u2.y >> 16));
    } else {
      const float4* fp = (const float4*)((const float*)A.filt_r + base);
      float4 v0 = fp[0], v1 = fp[1], v2 = fp[2];
      f[0] = v0.x; f[1] = v0.y; f[2] = v0.z; f[3] = v0.w;
      f[4] = v1.x; f[5] = v1.y; f[6] = v1.z; f[7] = v1.w;
      f[8] = v2.x; f[9] = v2.y; f[10] = v2.z; f[11] = v2.w;
    }
    float tacc = 0.f;
    int lb = lq * 12;
#pragma unroll
    for (int r = 0; r < 12; ++r) {
      float fv = f[r];
      int l = lb + r;
      tacc += fv * twl[l];
      acc0 += fv * qs[0][ci][l];
      acc1 += fv * qs[1][ci][l];
      acc2 += fv * qs[2][ci][l];
      acc3 += fv * qs[3][ci][l];
    }
    tacc += __shfl_xor(tacc, 1, 64);
    tacc += __shfl_xor(tacc, 2, 64);
    if (lq == 0) ws[WS_T + ((lay * 256 + c) * 256) + o0 + ol] = tacc;
  }
  acc0 += __shfl_xor(acc0, 1, 64); acc0 += __shfl_xor(acc0, 2, 64);
  acc1 += __shfl_xor(acc1, 1, 64); acc1 += __shfl_xor(acc1, 2, 64);
  acc2 += __shfl_xor(acc2, 1, 64); acc2 += __shfl_xor(acc2, 2, 64);
  acc3 += __shfl_xor(acc3, 1, 64); acc3 += __shfl_xor(acc3, 2, 64);
  if (lq == 0) {
    int po = o0 + ol;
    long pb = (long)(lay * 64 + cb) * 4 * 256;
    ws[WS_PART + pb + 0 * 256 + po] = acc0;
    ws[WS_PART + pb + 1 * 256 + po] = acc1;
    ws[WS_PART + pb + 2 * 256 + po] = acc2;
    ws[WS_PART + pb + 3 * 256 + po] = acc3;
  }
  // L3 warm for the chain kernel's w1/w2 reads.
  if (bx < 32) {
    long nbytes = 524288L * (bf ? 2 : 4);
    long per = nbytes / 32;
    long off = (long)bx * per;
    const char* p1 = (const char*)A.w1;
    const char* p2 = (const char*)A.w2;
    float acc = 0.f;
    for (long i = (long)t * 16; i < per; i += 256 * 16) {
      float4 v1 = *(const float4*)(p1 + off + i);
      float4 v2 = *(const float4*)(p2 + off + i);
      acc += v1.x + v2.x;
    }
    asm volatile("" :: "v"(acc));
  }
}

__device__ __forceinline__ void load_item(const Args& A, int idx, int bf,
                                          float4 xv[5], float4 ev[2]) {
  int n4 = idx % 60;
  int j = (idx / 60) % 121;
  int bb = idx / 7260;
  int n = n4 * 4;
#pragma unroll
  for (int ic = 0; ic < 5; ++ic)
    xv[ic] = ld4(A.x, ((long)((bb * 5 + ic) * 121 + j)) * 240 + n, bf);
#pragma unroll
  for (int oc = 0; oc < 2; ++oc)
    ev[oc] = ld4(A.eps, ((long)((bb * 2 + oc) * 121 + j)) * 240 + n, bf);
}

__device__ __forceinline__ void store_item(const Args& A, int idx, int bf,
                                           const float4 xv[5], const float4 ev[2],
                                           const float* sW4, const float* sBias) {
  int n4 = idx % 60;
  int j = (idx / 60) % 121;
  int bb = idx / 7260;
  int n = n4 * 4;
  float v[4][4];
#pragma unroll
  for (int o4 = 0; o4 < 4; ++o4) {
    float bias = sBias[bb * 4 + o4];
    float s0 = bias, s1 = bias, s2 = bias, s3 = bias;
#pragma unroll
    for (int ic = 0; ic < 5; ++ic) {
      float w = sW4[o4 * 5 + ic];
      s0 += w * xv[ic].x; s1 += w * xv[ic].y;
      s2 += w * xv[ic].z; s3 += w * xv[ic].w;
    }
    v[o4][0] = s0; v[o4][1] = s1; v[o4][2] = s2; v[o4][3] = s3;
  }
  const long NPO = (long)4 * 2 * 121 * 240;  // 232320
#pragma unroll
  for (int oc = 0; oc < 2; ++oc) {
    long eoff = ((long)((bb * 2 + oc) * 121 + j)) * 240 + n;
    float e0 = expf(v[oc + 2][0]), e1 = expf(v[oc + 2][1]);
    float e2 = expf(v[oc + 2][2]), e3 = expf(v[oc + 2][3]);
    st4(A.out, eoff, v[oc][0] + ev[oc].x * e0, v[oc][1] + ev[oc].y * e1,
        v[oc][2] + ev[oc].z * e2, v[oc][3] + ev[oc].w * e3, bf);        // sample
    st4(A.out, NPO + eoff, v[oc][0], v[oc][1], v[oc][2], v[oc][3], bf); // mu
    st4(A.out, 2 * NPO + eoff, v[oc + 2][0], v[oc + 2][1], v[oc + 2][2],
        v[oc + 2][3], bf);                                              // log_sigma
  }
}

// kchain: blocks 0..63 run the 4-layer chain (1 grid barrier/layer) + bias
// finalize; blocks 64..127 compute w_out·w_in, prefetch ALL output-stage
// x/eps into registers during the chain, then write all outputs after the
// final barrier. Chain blocks arrive-and-exit at the final barrier.
__global__ void __launch_bounds__(256) kchain(Args A) {
  int bf = detect_bf(A.wq);
  int t = threadIdx.x;
  int blk = blockIdx.x;
  float* ws = A.ws;
  int* bars = (int*)(ws + WS_BAR);

  if (blk >= 64) {
    __shared__ float sW4[20];
    __shared__ float sBias[16];
    if (blk == 64 && t < 160) {
      int e = t >> 3, sub8 = t & 7;  // e < 20
      int o4b = e / 5, ic = e - o4b * 5;
      float w = 0.f;
      for (int c = sub8; c < 256; c += 8)
        w += ldf(A.w_out, o4b * 256 + c, bf) * ldf(A.w_in, c * 5 + ic, bf);
      w += __shfl_xor(w, 1, 64);
      w += __shfl_xor(w, 2, 64);
      w += __shfl_xor(w, 4, 64);
      if (sub8 == 0) ws[WS_W4 + e] = w;
    }
    int idx0 = (blk - 64) * 256 + t;  // < 16384, always valid
    int idx1 = idx0 + 16384;
    float4 xv0[5], ev0[2], xv1[5], ev1[2];
    load_item(A, idx0, bf, xv0, ev0);
    bool has1 = idx1 < NOUT_ITEMS;
    if (has1) load_item(A, idx1, bf, xv1, ev1);
    gbar_arrive(bars, 4);
    gbar_wait(bars, 4, NBLK);
    if (t < 20) sW4[t] = *(volatile float*)(ws + WS_W4 + t);
    if (t >= 32 && t < 48) sBias[t - 32] = *(volatile float*)(ws + WS_BIAS + t - 32);
    __syncthreads();
    store_item(A, idx0, bf, xv0, ev0, sW4, sBias);
    if (has1) store_item(A, idx1, bf, xv1, ev1, sW4, sBias);
    return;
  }

  // ---- chain blocks ----
  __shared__ float sD[256];
  __shared__ float sG[256];
  __shared__ float ap[8][32];
  __shared__ float sAl[32];
  int b = blk >> 4, hc = blk & 15;
  int h0 = hc * 32;
  sD[t] = 0.f;

  for (int lay = 0; lay < 4; ++lay) {
    // g[t] = sum_cb PART + sum_c D[c]*T[c][t]
    float g = 0.f;
#pragma unroll 16
    for (int cb = 0; cb < 64; ++cb)
      g += ws[WS_PART + (((lay * 64 + cb) * 4 + b) * 256) + t];
    if (lay) {
#pragma unroll 16
      for (int c = 0; c < 256; ++c)
        g += sD[c] * ws[WS_T + ((lay * 256 + c) * 256) + t];
    }
    sG[t] = g;
    __syncthreads();
    // a[h] for h in this block's 32-chunk: 8 o-subranges x 32 h
    {
      int sub = t >> 5, hl = t & 31;
      float acc = 0.f;
#pragma unroll 8
      for (int r = 0; r < 32; ++r) {
        int o = sub * 32 + r;
        acc += sG[o] * ldf(A.w1, ((long)(lay * 256 + o)) * 512 + h0 + hl, bf);
      }
      ap[sub][hl] = acc;
    }
    __syncthreads();
    if (t < 32) {
      float v = ldf(A.b1, lay * 512 + h0 + t, bf);
#pragma unroll
      for (int r = 0; r < 8; ++r) v += ap[r][t];
      sAl[t] = 0.5f * v * (1.0f + erff(v * 0.7071067811865475f));  // exact gelu
    }
    __syncthreads();
    // delta partial for this h-chunk over all c=t
    float s = (hc == 0) ? ldf(A.b2, lay * 256 + t, bf) : 0.f;
#pragma unroll 8
    for (int r = 0; r < 32; ++r)
      s += sAl[r] * ldf(A.w2, ((long)(lay * 512 + h0 + r)) * 256 + t, bf);
    ws[WS_DP + (((lay * 4 + b) * NKC + hc) * 256) + t] = s;
    gbar_arrive(bars, lay);
    gbar_wait(bars, lay, 64);
    // fold this layer's delta into D
    float dsum = 0.f;
#pragma unroll
    for (int kc = 0; kc < NKC; ++kc)
      dsum += *(volatile float*)(ws + WS_DP + (((lay * 4 + b) * NKC + kc) * 256) + t);
    sD[t] += dsum;
    __syncthreads();
  }

  // bias finalize: one block per b (hc==0) has the complete D in sD
  if (hc == 0) {
    int o4 = t >> 6, sub = t & 63;
    float s = 0.f;
    for (int c = sub; c < 256; c += 64)
      s += ldf(A.w_out, o4 * 256 + c, bf) * (ldf(A.b_in, c, bf) + sD[c]);
    for (int dd = 32; dd; dd >>= 1) s += __shfl_xor(s, dd, 64);
    if (sub == 0) ws[WS_BIAS + b * 4 + o4] = ldf(A.b_out, o4, bf) + s;
  }
  gbar_arrive(bars, 4);  // no wait — nothing left to do
}

}  // namespace

extern "C" void kernel_launch(void* const* d_in, const int* in_sizes, int n_in,
                              void* d_out, int out_size, void* d_ws,
                              size_t ws_size, hipStream_t stream) {
  Args A;
  A.x = d_in[0]; A.eps = d_in[1]; A.Pmat = d_in[2]; A.wq = d_in[3];
  A.w_in = d_in[4]; A.b_in = d_in[5]; A.filt_r = d_in[6];
  // d_in[7] = filt_i: mathematically dead (m=0 coeffs are real).
  A.w1 = d_in[8]; A.b1 = d_in[9]; A.w2 = d_in[10]; A.b2 = d_in[11];
  A.w_out = d_in[12]; A.b_out = d_in[13];
  A.ws = (float*)d_ws;
  A.out = d_out;

  hipLaunchKernelGGL(k01_prep_xbar, dim3(606), dim3(256), 0, stream, A);
  hipLaunchKernelGGL(k3q, dim3(1024), dim3(256), 0, stream, A);
  hipLaunchKernelGGL(kchain, dim3(NBLK), dim3(256), 0, stream, A);
}

// Round 6
// 106.758 us; speedup vs baseline: 2.0971x; 1.3411x over previous
//
#include <hip/hip_runtime.h>
#include <hip/hip_bf16.h>

// ProbSFNO — algebraically collapsed: only m=0 spherical modes reach the output.
// filt_i is mathematically dead; per-layer state is a (B,EMBED) vector D.
// R4/R5 post-mortem: every barrier paid a full L2 writeback (buffer_wbl2 from
// the release fence) ~18us. R6 (this): cross-block data uses agent-scope
// write-through atomics (no wbl2), RELAXED arrivals after __syncthreads-drain,
// per-(lay,b) barriers among 16 blocks, layer-3 arrive-and-exit, bias/W4
// computed redundantly in out-blocks, deep-unrolled latency-bound loops.

namespace {

constexpr float kTwoPi = 6.283185307179586f;
constexpr int NKC = 16;   // h-chunks (32 wide) / delta split in the chain
constexpr int NBLK = 128; // kchain grid (co-resident: 128 <= 256 CUs)
constexpr int NOUT_ITEMS = 4 * 121 * 60;  // 29040 float4-wide output items

// ws layout (float offsets)
constexpr int WS_PW0  = 16;                  // [48][121] Pmat[l,0,j]*wq[j]
constexpr int WS_PBAR = 5824;                // [48] mean_j Pmat[l,0,j]
constexpr int WS_TW   = 5872;                // [48] 2pi*Pbar*SW
constexpr int WS_XBAR = 5920;                // [4][5][121] mean_lon x
constexpr int WS_BAR  = 8352;                // [64] int barrier counters
constexpr int WS_T    = 16384;               // [4][256][256]
constexpr int WS_PART = 278528;              // [4][64][4][256] term1 partials
constexpr int WS_DP   = 540672;              // [4lay][4b][16][256] delta partials

struct Args {
  const void *x, *eps, *Pmat, *wq, *w_in, *b_in, *filt_r;
  const void *w1, *b1, *w2, *b2, *w_out, *b_out;
  float* ws;
  void* out;
};

__device__ __forceinline__ float bf2f(unsigned short u) {
  union { unsigned int i; float f; } v; v.i = (unsigned int)u << 16; return v.f;
}
__device__ __forceinline__ unsigned short f2bf(float f) {
  union { float f; unsigned int i; } v; v.f = f;
  return (unsigned short)((v.i + 0x7FFFu + ((v.i >> 16) & 1u)) >> 16);
}
// Local dtype detect: wq[0] = 3.37e-4 if f32; a bf16-pair misread gives ~1e-3.
__device__ __forceinline__ int detect_bf(const void* wq) {
  float v = ((const float*)wq)[0];
  return !(v > 2.5e-4f && v < 4.5e-4f);
}
__device__ __forceinline__ float ldf(const void* p, long i, int bf) {
  return bf ? bf2f(((const unsigned short*)p)[i]) : ((const float*)p)[i];
}
__device__ __forceinline__ float4 ld4(const void* p, long e, int bf) {
  if (bf) {
    ushort4 u = *(const ushort4*)((const unsigned short*)p + e);
    return make_float4(bf2f(u.x), bf2f(u.y), bf2f(u.z), bf2f(u.w));
  }
  return *(const float4*)((const float*)p + e);
}
__device__ __forceinline__ void st4(void* p, long e, float a, float b, float c,
                                    float d, int bf) {
  if (bf) {
    ushort4 u; u.x = f2bf(a); u.y = f2bf(b); u.z = f2bf(c); u.w = f2bf(d);
    *(ushort4*)((unsigned short*)p + e) = u;
  } else {
    *(float4*)((float*)p + e) = make_float4(a, b, c, d);
  }
}

// Cross-block data: agent-scope write-through/bypass ops — never dirty in a
// non-coherent L2, so barriers need NO cache writeback (no buffer_wbl2).
__device__ __forceinline__ void stg_agent(float* p, float v) {
  __hip_atomic_store(p, v, __ATOMIC_RELAXED, __HIP_MEMORY_SCOPE_AGENT);
}
__device__ __forceinline__ float ldg_agent(const float* p) {
  return __hip_atomic_load(p, __ATOMIC_RELAXED, __HIP_MEMORY_SCOPE_AGENT);
}

// Barrier: arrival = RELAXED fetch_add after __syncthreads (whose vmcnt drain
// guarantees this block's agent-scope stores reached the coherence point).
__device__ __forceinline__ void gbar_arrive(int* bar) {
  __syncthreads();
  if (threadIdx.x == 0)
    __hip_atomic_fetch_add(bar, 1, __ATOMIC_RELAXED, __HIP_MEMORY_SCOPE_AGENT);
}
__device__ __forceinline__ void gbar_wait(int* bar, int n) {
  if (threadIdx.x == 0) {
    while (__hip_atomic_load(bar, __ATOMIC_RELAXED,
                             __HIP_MEMORY_SCOPE_AGENT) < n)
      __builtin_amdgcn_s_sleep(1);
  }
  __syncthreads();
}

// K01: blocks 0..604 = lon-means of x; block 605 = precomputes + bar zeroing.
__global__ void k01_prep_xbar(Args A) {
  int bf = detect_bf(A.wq);
  float* ws = A.ws;
  int t = threadIdx.x;
  if (blockIdx.x == 605) {
    if (t < 64) ((int*)(ws + WS_BAR))[t] = 0;
    for (int idx = t; idx < 48 * 121; idx += 256) {
      int l = idx / 121, j = idx - l * 121;
      float p = ldf(A.Pmat, (long)l * 48 * 121 + j, bf);  // Pmat[l][0][j]
      float w = ldf(A.wq, j, bf);
      ws[WS_PW0 + idx] = p * w;
    }
    if (t < 48) {
      float pb = 0.f, sw = 0.f;
      for (int j = 0; j < 121; ++j) {
        float p = ldf(A.Pmat, (long)t * 48 * 121 + j, bf);
        float w = ldf(A.wq, j, bf);
        pb += p; sw += p * w;
      }
      pb *= (1.0f / 121.0f);
      ws[WS_PBAR + t] = pb;
      ws[WS_TW + t] = kTwoPi * pb * sw;
    }
    return;
  }
  int wave = blockIdx.x * 4 + (t >> 6);
  int lane = t & 63;
  long base = (long)wave * 240;
  float s = 0.f;
  for (int e = lane; e < 240; e += 64) s += ldf(A.x, base + e, bf);
  for (int d = 32; d; d >>= 1) s += __shfl_xor(s, d, 64);
  if (lane == 0) ws[WS_XBAR + wave] = s * (1.0f / 240.0f);
}

// K3q: per-block q recompute + filt_r stream -> T, PART. Warms w1/w2 into L3.
__global__ void __launch_bounds__(256) k3q(Args A) {
  __shared__ float pw0[48 * 121];
  __shared__ float g0[16][121];
  __shared__ float qs[4][4][48];
  __shared__ float twl[48];
  int bf = detect_bf(A.wq);
  int t = threadIdx.x;
  int bx = blockIdx.x;
  int lay = bx >> 8;
  int rem = bx & 255;
  int cb = rem >> 2, ob = rem & 3;
  int c0 = cb * 4, o0 = ob * 64;
  int ol = t >> 2, lq = t & 3;  // thread owns (o0+ol, l in [lq*12, lq*12+12))
  float* ws = A.ws;
  if (t < 48) twl[t] = ws[WS_TW + t];
  for (int ii = t; ii < 48 * 121; ii += 256) pw0[ii] = ws[WS_PW0 + ii];
  for (int ii = t; ii < 16 * 121; ii += 256) {
    int pair = ii / 121, j = ii - pair * 121;
    int bb = pair >> 2, ci = pair & 3, c = c0 + ci;
    float h = ldf(A.b_in, c, bf);
#pragma unroll
    for (int ic = 0; ic < 5; ++ic)
      h += ldf(A.w_in, c * 5 + ic, bf) * ws[WS_XBAR + (bb * 5 + ic) * 121 + j];
    g0[pair][j] = kTwoPi * h;
  }
  __syncthreads();
  for (int dd = t; dd < 768; dd += 256) {
    int pair = dd / 48, l = dd - pair * 48;
    float q = 0.f;
    const float* pw = &pw0[l * 121];
    const float* g = &g0[pair][0];
    for (int j = 0; j < 121; ++j) q += g[j] * pw[j];
    qs[pair >> 2][pair & 3][l] = q * ws[WS_PBAR + l];
  }
  __syncthreads();

  float acc0 = 0.f, acc1 = 0.f, acc2 = 0.f, acc3 = 0.f;
#pragma unroll
  for (int ci = 0; ci < 4; ++ci) {
    int c = c0 + ci;
    long base = ((long)((lay * 256 + c) * 256 + (o0 + ol))) * 48 + lq * 12;
    float f[12];
    if (bf) {
      const uint2* up = (const uint2*)((const unsigned short*)A.filt_r + base);
      uint2 u0 = up[0], u1 = up[1], u2 = up[2];
      f[0] = bf2f((unsigned short)(u0.x & 0xFFFFu)); f[1] = bf2f((unsigned short)(u0.x >> 16));
      f[2] = bf2f((unsigned short)(u0.y & 0xFFFFu)); f[3] = bf2f((unsigned short)(u0.y >> 16));
      f[4] = bf2f((unsigned short)(u1.x & 0xFFFFu)); f[5] = bf2f((unsigned short)(u1.x >> 16));
      f[6] = bf2f((unsigned short)(u1.y & 0xFFFFu)); f[7] = bf2f((unsigned short)(u1.y >> 16));
      f[8] = bf2f((unsigned short)(u2.x & 0xFFFFu)); f[9] = bf2f((unsigned short)(u2.x >> 16));
      f[10] = bf2f((unsigned short)(u2.y & 0xFFFFu)); f[11] = bf2f((unsigned short)(u2.y >> 16));
    } else {
      const float4* fp = (const float4*)((const float*)A.filt_r + base);
      float4 v0 = fp[0], v1 = fp[1], v2 = fp[2];
      f[0] = v0.x; f[1] = v0.y; f[2] = v0.z; f[3] = v0.w;
      f[4] = v1.x; f[5] = v1.y; f[6] = v1.z; f[7] = v1.w;
      f[8] = v2.x; f[9] = v2.y; f[10] = v2.z; f[11] = v2.w;
    }
    float tacc = 0.f;
    int lb = lq * 12;
#pragma unroll
    for (int r = 0; r < 12; ++r) {
      float fv = f[r];
      int l = lb + r;
      tacc += fv * twl[l];
      acc0 += fv * qs[0][ci][l];
      acc1 += fv * qs[1][ci][l];
      acc2 += fv * qs[2][ci][l];
      acc3 += fv * qs[3][ci][l];
    }
    tacc += __shfl_xor(tacc, 1, 64);
    tacc += __shfl_xor(tacc, 2, 64);
    if (lq == 0) ws[WS_T + ((lay * 256 + c) * 256) + o0 + ol] = tacc;
  }
  acc0 += __shfl_xor(acc0, 1, 64); acc0 += __shfl_xor(acc0, 2, 64);
  acc1 += __shfl_xor(acc1, 1, 64); acc1 += __shfl_xor(acc1, 2, 64);
  acc2 += __shfl_xor(acc2, 1, 64); acc2 += __shfl_xor(acc2, 2, 64);
  acc3 += __shfl_xor(acc3, 1, 64); acc3 += __shfl_xor(acc3, 2, 64);
  if (lq == 0) {
    int po = o0 + ol;
    long pb = (long)(lay * 64 + cb) * 4 * 256;
    ws[WS_PART + pb + 0 * 256 + po] = acc0;
    ws[WS_PART + pb + 1 * 256 + po] = acc1;
    ws[WS_PART + pb + 2 * 256 + po] = acc2;
    ws[WS_PART + pb + 3 * 256 + po] = acc3;
  }
  // L3 warm for the chain kernel's w1/w2 reads.
  if (bx < 32) {
    long nbytes = 524288L * (bf ? 2 : 4);
    long per = nbytes / 32;
    long off = (long)bx * per;
    const char* p1 = (const char*)A.w1;
    const char* p2 = (const char*)A.w2;
    float acc = 0.f;
    for (long i = (long)t * 16; i < per; i += 256 * 16) {
      float4 v1 = *(const float4*)(p1 + off + i);
      float4 v2 = *(const float4*)(p2 + off + i);
      acc += v1.x + v2.x;
    }
    asm volatile("" :: "v"(acc));
  }
}

__device__ __forceinline__ void load_item(const Args& A, int idx, int bf,
                                          float4 xv[5], float4 ev[2]) {
  int n4 = idx % 60;
  int j = (idx / 60) % 121;
  int bb = idx / 7260;
  int n = n4 * 4;
#pragma unroll
  for (int ic = 0; ic < 5; ++ic)
    xv[ic] = ld4(A.x, ((long)((bb * 5 + ic) * 121 + j)) * 240 + n, bf);
#pragma unroll
  for (int oc = 0; oc < 2; ++oc)
    ev[oc] = ld4(A.eps, ((long)((bb * 2 + oc) * 121 + j)) * 240 + n, bf);
}

__device__ __forceinline__ void store_item(const Args& A, int idx, int bf,
                                           const float4 xv[5], const float4 ev[2],
                                           const float* sW4, const float* sBias) {
  int n4 = idx % 60;
  int j = (idx / 60) % 121;
  int bb = idx / 7260;
  int n = n4 * 4;
  float v[4][4];
#pragma unroll
  for (int o4 = 0; o4 < 4; ++o4) {
    float bias = sBias[bb * 4 + o4];
    float s0 = bias, s1 = bias, s2 = bias, s3 = bias;
#pragma unroll
    for (int ic = 0; ic < 5; ++ic) {
      float w = sW4[o4 * 5 + ic];
      s0 += w * xv[ic].x; s1 += w * xv[ic].y;
      s2 += w * xv[ic].z; s3 += w * xv[ic].w;
    }
    v[o4][0] = s0; v[o4][1] = s1; v[o4][2] = s2; v[o4][3] = s3;
  }
  const long NPO = (long)4 * 2 * 121 * 240;  // 232320
#pragma unroll
  for (int oc = 0; oc < 2; ++oc) {
    long eoff = ((long)((bb * 2 + oc) * 121 + j)) * 240 + n;
    float e0 = expf(v[oc + 2][0]), e1 = expf(v[oc + 2][1]);
    float e2 = expf(v[oc + 2][2]), e3 = expf(v[oc + 2][3]);
    st4(A.out, eoff, v[oc][0] + ev[oc].x * e0, v[oc][1] + ev[oc].y * e1,
        v[oc][2] + ev[oc].z * e2, v[oc][3] + ev[oc].w * e3, bf);        // sample
    st4(A.out, NPO + eoff, v[oc][0], v[oc][1], v[oc][2], v[oc][3], bf); // mu
    st4(A.out, 2 * NPO + eoff, v[oc + 2][0], v[oc + 2][1], v[oc + 2][2],
        v[oc + 2][3], bf);                                              // log_sigma
  }
}

// kchain: blocks 0..63 = four independent per-b chains (16 blocks each,
// per-(lay,b) barriers; layer 3 is arrive-and-exit). Blocks 64..127 prefetch
// x/eps + compute W4 during the chain, wait for the four layer-3 counters,
// then locally finalize D/bias and write all outputs.
__global__ void __launch_bounds__(256) kchain(Args A) {
  int bf = detect_bf(A.wq);
  int t = threadIdx.x;
  int blk = blockIdx.x;
  float* ws = A.ws;
  int* bars = (int*)(ws + WS_BAR);

  if (blk >= 64) {
    __shared__ float sW4[20];
    __shared__ float sBias[16];
    __shared__ float sDD[4][256];
    int idx0 = (blk - 64) * 256 + t;  // < 16384, always valid
    int idx1 = idx0 + 16384;
    float4 xv0[5], ev0[2], xv1[5], ev1[2];
    load_item(A, idx0, bf, xv0, ev0);
    bool has1 = idx1 < NOUT_ITEMS;
    if (has1) load_item(A, idx1, bf, xv1, ev1);
    if (t < 160) {  // local w_out·w_in (redundant per block, hidden by chain)
      int e = t >> 3, sub8 = t & 7;  // e < 20
      int o4b = e / 5, ic = e - o4b * 5;
      float w = 0.f;
      for (int c = sub8; c < 256; c += 8)
        w += ldf(A.w_out, o4b * 256 + c, bf) * ldf(A.w_in, c * 5 + ic, bf);
      w += __shfl_xor(w, 1, 64);
      w += __shfl_xor(w, 2, 64);
      w += __shfl_xor(w, 4, 64);
      if (sub8 == 0) sW4[e] = w;
    }
    if (t == 0) {  // wait for all four b-chains' final layer
      for (int b = 0; b < 4; ++b)
        while (__hip_atomic_load(&bars[12 + b], __ATOMIC_RELAXED,
                                 __HIP_MEMORY_SCOPE_AGENT) < 16)
          __builtin_amdgcn_s_sleep(1);
    }
    __syncthreads();
#pragma unroll
    for (int b = 0; b < 4; ++b) {  // D[b][t] from the 64 delta partials
      float d = 0.f;
#pragma unroll 16
      for (int u = 0; u < 64; ++u) {
        int l = u >> 4, kc = u & 15;
        d += ldg_agent(ws + WS_DP + (((l * 4 + b) * NKC + kc) * 256) + t);
      }
      sDD[b][t] = d;
    }
    __syncthreads();
    {
      int pair = t >> 4, sub = t & 15;  // pair = b*4+o4
      int b = pair >> 2, o4 = pair & 3;
      float s = 0.f;
      for (int c = sub; c < 256; c += 16)
        s += ldf(A.w_out, o4 * 256 + c, bf) * (ldf(A.b_in, c, bf) + sDD[b][c]);
      s += __shfl_xor(s, 1, 64);
      s += __shfl_xor(s, 2, 64);
      s += __shfl_xor(s, 4, 64);
      s += __shfl_xor(s, 8, 64);
      if (sub == 0) sBias[pair] = ldf(A.b_out, o4, bf) + s;
    }
    __syncthreads();
    store_item(A, idx0, bf, xv0, ev0, sW4, sBias);
    if (has1) store_item(A, idx1, bf, xv1, ev1, sW4, sBias);
    return;
  }

  // ---- chain blocks: b-chain = blk>>4, h-chunk = blk&15 ----
  __shared__ float sD[256];
  __shared__ float sG[256];
  __shared__ float ap[8][32];
  __shared__ float sAl[32];
  int b = blk >> 4, hc = blk & 15;
  int h0 = hc * 32;
  sD[t] = 0.f;

  for (int lay = 0; lay < 4; ++lay) {
    // g[t] = sum_cb PART + sum_c D[c]*T[c][t]   (deep ILP: L3-latency-bound)
    float g = 0.f;
#pragma unroll 32
    for (int cb = 0; cb < 64; ++cb)
      g += ws[WS_PART + (((lay * 64 + cb) * 4 + b) * 256) + t];
    if (lay) {
#pragma unroll 32
      for (int c = 0; c < 256; ++c)
        g += sD[c] * ws[WS_T + ((lay * 256 + c) * 256) + t];
    }
    sG[t] = g;
    __syncthreads();
    {  // a[h] for this block's 32-chunk: 8 o-subranges x 32 h
      int sub = t >> 5, hl = t & 31;
      float acc = 0.f;
#pragma unroll
      for (int r = 0; r < 32; ++r) {
        int o = sub * 32 + r;
        acc += sG[o] * ldf(A.w1, ((long)(lay * 256 + o)) * 512 + h0 + hl, bf);
      }
      ap[sub][hl] = acc;
    }
    __syncthreads();
    if (t < 32) {
      float v = ldf(A.b1, lay * 512 + h0 + t, bf);
#pragma unroll
      for (int r = 0; r < 8; ++r) v += ap[r][t];
      sAl[t] = 0.5f * v * (1.0f + erff(v * 0.7071067811865475f));  // exact gelu
    }
    __syncthreads();
    // delta partial for this h-chunk over all c=t (agent write-through)
    float s = (hc == 0) ? ldf(A.b2, lay * 256 + t, bf) : 0.f;
#pragma unroll
    for (int r = 0; r < 32; ++r)
      s += sAl[r] * ldf(A.w2, ((long)(lay * 512 + h0 + r)) * 256 + t, bf);
    stg_agent(ws + WS_DP + (((lay * 4 + b) * NKC + hc) * 256) + t, s);
    gbar_arrive(&bars[lay * 4 + b]);
    if (lay == 3) return;  // out-blocks take it from here
    gbar_wait(&bars[lay * 4 + b], 16);
    float dsum = 0.f;
#pragma unroll
    for (int kc = 0; kc < NKC; ++kc)
      dsum += ldg_agent(ws + WS_DP + (((lay * 4 + b) * NKC + kc) * 256) + t);
    sD[t] += dsum;
    __syncthreads();
  }
}

}  // namespace

extern "C" void kernel_launch(void* const* d_in, const int* in_sizes, int n_in,
                              void* d_out, int out_size, void* d_ws,
                              size_t ws_size, hipStream_t stream) {
  Args A;
  A.x = d_in[0]; A.eps = d_in[1]; A.Pmat = d_in[2]; A.wq = d_in[3];
  A.w_in = d_in[4]; A.b_in = d_in[5]; A.filt_r = d_in[6];
  // d_in[7] = filt_i: mathematically dead (m=0 coeffs are real).
  A.w1 = d_in[8]; A.b1 = d_in[9]; A.w2 = d_in[10]; A.b2 = d_in[11];
  A.w_out = d_in[12]; A.b_out = d_in[13];
  A.ws = (float*)d_ws;
  A.out = d_out;

  hipLaunchKernelGGL(k01_prep_xbar, dim3(606), dim3(256), 0, stream, A);
  hipLaunchKernelGGL(k3q, dim3(1024), dim3(256), 0, stream, A);
  hipLaunchKernelGGL(kchain, dim3(NBLK), dim3(256), 0, stream, A);
}